// Round 1
// baseline (512.639 us; speedup 1.0000x reference)
//
#include <hip/hip_runtime.h>
#include <hip/hip_bf16.h>

#define BQ 4096
#define SEQ 120
#define DIM 256
#define CELLS 36
#define RDIM 48
#define BM 128
#define MTOT (BQ*CELLS)   // 147456
#define NBLK (MTOT/BM)    // 1152

typedef __bf16 bf16x8 __attribute__((ext_vector_type(8)));
typedef __bf16 bf16x4 __attribute__((ext_vector_type(4)));
typedef float  f32x4  __attribute__((ext_vector_type(4)));
typedef unsigned int u32x4 __attribute__((ext_vector_type(4)));

__device__ __forceinline__ float gelu_f(float x){
  return 0.5f * x * (1.0f + erff(x * 0.7071067811865476f));
}

// ---- prep: conv_w (256,256,2,2) f32 -> W_bt bf16 [o][k], k = pos*256 + c
__global__ void prep_kernel(const float* __restrict__ conv_w, __bf16* __restrict__ W_bt){
  int o = blockIdx.x;
  int k = threadIdx.x;
  int c = k & 255, pos = k >> 8;
  W_bt[o*1024 + k] = (__bf16)conv_w[o*1024 + c*4 + pos];
}

// ---- main fused kernel: patch-GEMM (M=147456,N=256,K=1024) + gelu + (256->48) GEMM + gelu -> G
__global__ __launch_bounds__(512, 2) void main_kernel(
    const float* __restrict__ X, const float* __restrict__ P,
    const __bf16* __restrict__ W_bt, const float* __restrict__ conv_b,
    const float* __restrict__ red_w, const float* __restrict__ red_b,
    float* __restrict__ G)
{
  // LDS map: [0,16K)x2 A dbuf | [32K,64K)+[64K,96K) B dbuf | [96K,120K) red_w bf16
  // Y (gelu'd conv out, bf16 [128][256]) overlaps [0,64K) after the K-loop.
  __shared__ __align__(16) char sm[122880];
  const int tid  = threadIdx.x;
  const int lane = tid & 63;
  const int wave = tid >> 6;
  const int wm = wave >> 2, wn = wave & 3;
  const int lr = lane & 15, lk = lane >> 4;

  // staging roles
  const int arow = tid >> 2, aq = tid & 3;   // A: 128 rows x 4 quarters of 16 cols
  const int brow = tid >> 1, bh = tid & 1;   // B: 256 rows x 2 halves of 32 cols

  // row -> the 4 patch-source pointers (one per kernel position)
  const int m    = blockIdx.x * BM + arow;
  const int bidx = m / CELLS;
  const int cell = m - bidx * CELLS;
  const int ci = cell / 6, cj = cell - ci*6;
  const float* rptr[4];
  #pragma unroll
  for (int pos = 0; pos < 4; ++pos){
    int tok = 24*ci + 12*(pos>>1) + 2*cj + (pos&1);
    rptr[pos] = (tok < SEQ) ? (X + ((size_t)bidx*SEQ + tok)*DIM) : P;
  }

  f32x4 areg[4];
  u32x4 breg[4];

  auto LOADG = [&](int s){
    const float* srcA = rptr[s>>2] + ((s&3)*64 + aq*16);
    #pragma unroll
    for (int u=0;u<4;u++) areg[u] = ((const f32x4*)srcA)[u];
    const u32x4* srcB = (const u32x4*)(W_bt + (size_t)brow*1024 + s*64 + bh*32);
    #pragma unroll
    for (int u=0;u<4;u++) breg[u] = srcB[u];
  };
  auto WRITE = [&](int buf){
    bf16x8 p0, p1;
    const float* af = (const float*)areg;
    #pragma unroll
    for (int u=0;u<8;u++){ p0[u] = (__bf16)af[u]; p1[u] = (__bf16)af[u+8]; }
    int basA = buf*16384 + arow*128 + aq*32;
    int keyA = (arow&7)<<4;
    *(bf16x8*)(sm + ((basA     ) ^ keyA)) = p0;
    *(bf16x8*)(sm + ((basA + 16) ^ keyA)) = p1;
    int basB = 32768 + buf*32768 + brow*128 + bh*64;
    int keyB = (brow&7)<<4;
    #pragma unroll
    for (int u=0;u<4;u++) *(u32x4*)(sm + ((basB + u*16) ^ keyB)) = breg[u];
  };

  // stage red_w (48x256 f32 -> bf16, swizzled) into [96K,120K)
  #pragma unroll
  for (int p=0;p<6;p++){
    int e4 = tid + p*512;                 // 3072 float4s total
    int r = e4 >> 6, n0 = (e4 & 63) << 2;
    f32x4 v = ((const f32x4*)red_w)[e4];
    bf16x4 w;
    #pragma unroll
    for (int u=0;u<4;u++) w[u] = (__bf16)v[u];
    *(bf16x4*)(sm + 98304 + ((r*512 + n0*2) ^ ((r&7)<<4))) = w;
  }

  f32x4 acc[4][4];
  #pragma unroll
  for (int a=0;a<4;a++)
    #pragma unroll
    for (int b=0;b<4;b++) acc[a][b] = (f32x4){0.f,0.f,0.f,0.f};

  LOADG(0); WRITE(0);
  __syncthreads();

  for (int s = 0; s < 16; ++s){
    const int cur = s & 1;
    if (s < 15) LOADG(s+1);               // issue next-tile global loads early (hide under MFMA)
    const int abase = cur*16384;
    const int bbase = 32768 + cur*32768;
    const int key = (lr&7)<<4;
    #pragma unroll
    for (int kk=0; kk<2; ++kk){
      bf16x8 av[4], bv[4];
      #pragma unroll
      for (int mi=0; mi<4; ++mi){
        int row = wm*64 + mi*16 + lr;
        av[mi] = *(const bf16x8*)(sm + abase + ((row*128 + kk*64 + lk*16) ^ key));
      }
      #pragma unroll
      for (int ni=0; ni<4; ++ni){
        int col = wn*64 + ni*16 + lr;
        bv[ni] = *(const bf16x8*)(sm + bbase + ((col*128 + kk*64 + lk*16) ^ key));
      }
      #pragma unroll
      for (int mi=0; mi<4; ++mi)
        #pragma unroll
        for (int ni=0; ni<4; ++ni)
          acc[mi][ni] = __builtin_amdgcn_mfma_f32_16x16x32_bf16(av[mi], bv[ni], acc[mi][ni], 0,0,0);
    }
    if (s < 15) WRITE((s+1)&1);
    __syncthreads();
  }

  // ---- epilogue 1: conv bias + gelu -> Y bf16 LDS [128][256], swizzled by row
  #pragma unroll
  for (int ni=0; ni<4; ++ni){
    int n = wn*64 + ni*16 + lr;
    float cb = conv_b[n];
    #pragma unroll
    for (int mi=0; mi<4; ++mi){
      int rowb = wm*64 + mi*16 + lk*4;
      #pragma unroll
      for (int reg=0; reg<4; ++reg){
        int row = rowb + reg;
        float y = gelu_f(acc[mi][ni][reg] + cb);
        *(__bf16*)(sm + ((row*512 + n*2) ^ ((row&7)<<4))) = (__bf16)y;
      }
    }
  }
  __syncthreads();

  // ---- GEMM2: G = gelu(Y @ red_w^T + red_b); wave w owns rows [w*16, w*16+16)
  f32x4 acc2[3];
  #pragma unroll
  for (int nf=0;nf<3;nf++) acc2[nf] = (f32x4){0.f,0.f,0.f,0.f};
  const int rowY = wave*16 + lr;
  const int keyY = (lr&7)<<4;
  #pragma unroll
  for (int kk=0; kk<8; ++kk){
    bf16x8 a2 = *(const bf16x8*)(sm + ((rowY*512 + kk*64 + lk*16) ^ keyY));
    #pragma unroll
    for (int nf=0; nf<3; ++nf){
      int rr = nf*16 + lr;
      bf16x8 b2 = *(const bf16x8*)(sm + 98304 + ((rr*512 + kk*64 + lk*16) ^ keyY));
      acc2[nf] = __builtin_amdgcn_mfma_f32_16x16x32_bf16(a2, b2, acc2[nf], 0,0,0);
    }
  }
  const int growb = blockIdx.x*BM + wave*16 + lk*4;
  #pragma unroll
  for (int nf=0; nf<3; ++nf){
    int rr = nf*16 + lr;
    float rb = red_b[rr];
    #pragma unroll
    for (int reg=0; reg<4; ++reg){
      G[(size_t)(growb+reg)*RDIM + rr] = gelu_f(acc2[nf][reg] + rb);
    }
  }
}

// ---- head: pool over 36 cells + 16 residual blocks + final linear. 32 batches/block.
__global__ __launch_bounds__(256) void head_kernel(
    const float* __restrict__ G,
    const float* __restrict__ res_w1, const float* __restrict__ res_b1,
    const float* __restrict__ res_w2, const float* __restrict__ res_b2,
    const float* __restrict__ out_w,  const float* __restrict__ out_b,
    float* __restrict__ out)
{
  __shared__ float Hs[32][48];
  __shared__ float Ys[32][48];
  __shared__ float Ws[48*49];   // +1 row pad: stride 49 avoids 2-bank conflicts
  const int t  = threadIdx.x;
  const int b0 = blockIdx.x * 32;

  #pragma unroll
  for (int p=0;p<6;p++){
    int idx = p*256 + t; int bl = idx/48; int j = idx - bl*48;
    const float* g = G + ((size_t)(b0+bl)*CELLS)*RDIM + j;
    float s = 0.f;
    #pragma unroll
    for (int c=0;c<CELLS;c++) s += g[c*RDIM];
    Hs[bl][j] = s * (1.0f/36.0f);
  }
  __syncthreads();

  for (int l=0;l<16;l++){
    const float* w1 = res_w1 + l*2304;
    for (int p=t; p<2304; p+=256){ int j=p/48, r=p-j*48; Ws[j*49+r] = w1[p]; }
    __syncthreads();
    #pragma unroll
    for (int p=0;p<6;p++){
      int idx = p*256 + t; int bl = idx/48; int j = idx - bl*48;
      float s = res_b1[l*48 + j];
      #pragma unroll
      for (int r=0;r<48;r++) s += Hs[bl][r]*Ws[j*49+r];
      Ys[bl][j] = gelu_f(s);
    }
    __syncthreads();
    const float* w2 = res_w2 + l*2304;
    for (int p=t; p<2304; p+=256){ int j=p/48, r=p-j*48; Ws[j*49+r] = w2[p]; }
    __syncthreads();
    #pragma unroll
    for (int p=0;p<6;p++){
      int idx = p*256 + t; int bl = idx/48; int j = idx - bl*48;
      float s = res_b2[l*48 + j];
      #pragma unroll
      for (int r=0;r<48;r++) s += Ys[bl][r]*Ws[j*49+r];
      Hs[bl][j] += s;
    }
    __syncthreads();
  }

  if (t < 32){
    float s = 0.f;
    #pragma unroll
    for (int j=0;j<48;j++) s += Hs[t][j]*out_w[j];
    out[b0 + t] = s + out_b[0];
  }
}

extern "C" void kernel_launch(void* const* d_in, const int* in_sizes, int n_in,
                              void* d_out, int out_size, void* d_ws, size_t ws_size,
                              hipStream_t stream) {
  const float* X      = (const float*)d_in[0];
  const float* P      = (const float*)d_in[1];
  const float* conv_w = (const float*)d_in[2];
  const float* conv_b = (const float*)d_in[3];
  const float* red_w  = (const float*)d_in[4];
  const float* red_b  = (const float*)d_in[5];
  const float* res_w1 = (const float*)d_in[6];
  const float* res_b1 = (const float*)d_in[7];
  const float* res_w2 = (const float*)d_in[8];
  const float* res_b2 = (const float*)d_in[9];
  const float* out_w  = (const float*)d_in[10];
  const float* out_b  = (const float*)d_in[11];
  float* out = (float*)d_out;

  __bf16* W_bt = (__bf16*)d_ws;                        // 512 KB
  float*  G    = (float*)((char*)d_ws + 512*1024);     // 28.3 MB

  prep_kernel<<<256, 1024, 0, stream>>>(conv_w, W_bt);
  main_kernel<<<NBLK, 512, 0, stream>>>(X, P, W_bt, conv_b, red_w, red_b, G);
  head_kernel<<<BQ/32, 256, 0, stream>>>(G, res_w1, res_b1, res_w2, res_b2, out_w, out_b, out);
}